// Round 8
// baseline (1448.074 us; speedup 1.0000x reference)
//
#include <hip/hip_runtime.h>
#include <hip/hip_fp16.h>
#include <cstdint>
#include <cstddef>

// Problem dims
#define B_    64
#define T_    256
#define D_    512
#define U_    500
#define UP_   512            // padded units
#define NCOL_ 2048           // 4*UP_
#define K_    1024           // D_ + UP_

typedef _Float16 f16x8 __attribute__((ext_vector_type(8)));
typedef float    f32x4 __attribute__((ext_vector_type(4)));
typedef int      i32x4 __attribute__((ext_vector_type(4)));

// ---- workspace layout (bytes) ----
#define OFF_X   0ull                         // x fp16: 64*256*512*2        = 16777216
#define OFF_W   16777216ull                  // Wcomb fp16: 2*2048*1024*2   = 8388608
#define OFF_B   25165824ull                  // bcomb f32: 2*2048*4         = 16384
#define OFF_H   25182208ull                  // h_buf fp16: 8*2*8192*2      = 262144

// ---- LDS layout (bytes), dynamic 136192 ----
// per-wave private x dbuf: w*32768 + parity*16384, 16 rows * 1024B (swizzled)
// per-wave z transpose:    131072 + w*1280  (16 cols * 20 words f32)
#define LZ_BASE 131072
#define LDS_BYTES 136192

#define TAGMASK 0x0003000300030003ull

#define GLD_LDS16(g, l) \
  __builtin_amdgcn_global_load_lds((const __attribute__((address_space(1))) void*)(g), \
                                   (__attribute__((address_space(3))) void*)(l), 16, 0, 0)

// ============================ prep kernels ============================

__global__ void prep_x(const float* __restrict__ x, _Float16* __restrict__ xf) {
  size_t base = ((size_t)blockIdx.x * 256 + threadIdx.x) * 8;
  const float4* p = (const float4*)(x + base);
  float4 a = p[0], b = p[1];
  f16x8 v;
  v[0] = (_Float16)a.x; v[1] = (_Float16)a.y; v[2] = (_Float16)a.z; v[3] = (_Float16)a.w;
  v[4] = (_Float16)b.x; v[5] = (_Float16)b.y; v[6] = (_Float16)b.z; v[7] = (_Float16)b.w;
  *(f16x8*)(xf + base) = v;
}

// W repack: col c = ut*64 + w*16 + g*4 + j  ->  (gate g, unit ug = ut*16 + w*4 + j)
__global__ void prep_w(const float* __restrict__ Wkf, const float* __restrict__ Wrf,
                       const float* __restrict__ Wkb, const float* __restrict__ Wrb,
                       const float* __restrict__ bf,  const float* __restrict__ bb,
                       _Float16* __restrict__ Wc, float* __restrict__ bcomb) {
  size_t gid = (size_t)blockIdx.x * 256 + threadIdx.x;
  int dir = (int)(gid >> 18);
  int rem = (int)(gid & 262143);
  int col = rem >> 7;
  int k0  = (rem & 127) << 3;
  const float* Wk = dir ? Wkb : Wkf;
  const float* Wr = dir ? Wrb : Wrf;
  int utc = col >> 6, wv = (col >> 4) & 3, g = (col >> 2) & 3, j = col & 3;
  int ug = utc * 16 + wv * 4 + j;
  bool valid = (ug < U_);
  int c4 = g * U_ + ug;
  f16x8 out;
#pragma unroll
  for (int kk = 0; kk < 8; ++kk) {
    int k = k0 + kk;
    float v = 0.f;
    if (valid) {
      if (k < D_) v = Wk[(size_t)k * (4 * U_) + c4];
      else { int u = k - D_; if (u < U_) v = Wr[(size_t)u * (4 * U_) + c4]; }
    }
    out[kk] = (_Float16)v;
  }
  *(f16x8*)(Wc + ((size_t)dir * NCOL_ + col) * K_ + k0) = out;

  if (gid < 4096) {
    int d2 = (int)(gid >> 11), c2 = (int)(gid & 2047);
    int ut2 = c2 >> 6, wv2 = (c2 >> 4) & 3, g2 = (c2 >> 2) & 3, j2 = c2 & 3;
    int ug2 = ut2 * 16 + wv2 * 4 + j2;
    const float* bs = d2 ? bb : bf;
    bcomb[gid] = (ug2 < U_) ? bs[g2 * U_ + ug2] : 0.f;
  }
}

// h_buf layout: [gi][parity][p=u>>4][row][u&15] fp16, 2-bit step tags in-band.
__global__ void prep_hb(const float* __restrict__ hf, const float* __restrict__ hb,
                        _Float16* __restrict__ hbuf) {
  int idx = blockIdx.x * 256 + threadIdx.x;    // < 65536
  int dir = idx >> 15;
  int rem = idx & 32767;
  int bt = rem >> 13, r = (rem >> 9) & 15, u = rem & 511;
  const float* h0 = dir ? hb : hf;
  float v = (u < U_) ? h0[(size_t)(bt * 16 + r) * U_ + u] : 0.f;
  int gi = dir * 4 + bt;
  union { _Float16 f; unsigned short s; } cv;
  cv.f = (_Float16)v;
  cv.s &= 0xFFFC;   // tag = 0
  ((unsigned short*)hbuf)[(size_t)(gi * 2 + 0) * 8192 + (u >> 4) * 256 + r * 16 + (u & 15)] = cv.s;
}

// ============================ persistent scan ============================
// 256 blocks (1/CU), 256 threads. Block = (dir, bt, ut): 16 rows x 16 units.
// FULLY INDEPENDENT WAVES: wave w owns units [w*4, w*4+4) x all 4 gates x all
// 16 rows, full K=1024. W fragments pinned in VGPRs (anti-remat asm). Private
// per-wave x dbuf in LDS. Gate combine via wave-local LDS transpose
// (lgkmcnt-only). h exchange via tagged 8B agent atomics. ZERO barriers.
__global__ __launch_bounds__(256, 1) void lstm_scan(
    const _Float16* __restrict__ xf, const _Float16* __restrict__ Wc,
    const float* __restrict__ bc, const float* __restrict__ cf,
    const float* __restrict__ cb, _Float16* __restrict__ hbuf,
    float* __restrict__ y)
{
  extern __shared__ __align__(16) char lds[];
  const int tid  = threadIdx.x;
  const int lane = tid & 63;
  const int w    = tid >> 6;        // wave id: owns units w*4..w*4+3
  const int bid  = blockIdx.x;
  const int grp  = bid & 7;         // group -> same XCD under round-robin (perf only)
  const int dir  = grp >> 2;
  const int bt   = grp & 3;
  const int ut   = bid >> 3;

  const int c15  = lane & 15;       // MFMA col (=g*4+j) / A row
  const int kg   = lane >> 4;       // k-group
  const int arow = c15;

  // ---- B-fragments -> pinned registers (32 x 16B = 128 VGPR) ----
  i32x4 bw[32];
  {
    const _Float16* wbase = Wc + ((size_t)dir * NCOL_ + (size_t)(ut * 64 + w * 16)) * K_;
    const _Float16* cl = wbase + (size_t)c15 * K_ + kg * 8;
#pragma unroll
    for (int ks = 0; ks < 32; ++ks)
      bw[ks] = *(const i32x4*)(cl + ks * 32);
#pragma unroll
    for (int ks = 0; ks < 32; ++ks)
      asm volatile("" : "+v"(bw[ks]));   // opaque: cannot be rematerialized
  }

  // owner mapping for gate/publish: lane L -> (row r = L>>2, unit j = L&3)
  const int orow = lane >> 2, oj = lane & 3;
  const int ug0 = ut * 16 + w * 4 + oj;
  float bg[4];
#pragma unroll
  for (int g = 0; g < 4; ++g) bg[g] = bc[dir * NCOL_ + ut * 64 + w * 16 + g * 4 + oj];
  const float* cin = dir ? cb : cf;
  float c = (ug0 < U_) ? cin[(size_t)(bt * 16 + orow) * U_ + ug0] : 0.f;

  const int gi = dir * 4 + bt;
  _Float16* hb = hbuf + (size_t)gi * 2 * 8192;
  char* xpriv = lds + w * 32768;
  float* zwf = (float*)(lds + LZ_BASE + w * 1280);

  // stage x[0] -> parity0, x[1] -> parity1 (private; 16 rows each)
#pragma unroll
  for (int tt = 0; tt < 2; ++tt) {
    const int t_x0 = dir ? (T_ - 1 - tt) : tt;
    char* dst = xpriv + tt * 16384;
    for (int r = 0; r < 16; ++r) {
      const char* src = (const char*)(xf + ((size_t)(bt * 16 + r) * T_ + t_x0) * D_)
                        + ((lane ^ (r & 7)) << 4);
      GLD_LDS16(src, dst + r * 1024);
    }
  }

#pragma unroll 1
  for (int t = 0; t < T_; ++t) {
    const int t_x = dir ? (T_ - 1 - t) : t;

    // ---- poll-issue: 32 agent-coherent u64 loads (full h, this wave's frags) ----
    const unsigned long long* hr =
        (const unsigned long long*)(hb + (size_t)(t & 1) * 8192);
    unsigned long long v[32];
#pragma unroll
    for (int ks = 0; ks < 16; ++ks) {
      int bidx = (ks * 2 + (kg >> 1)) * 64 + c15 * 4 + (kg & 1) * 2;
      v[2*ks]   = __hip_atomic_load(hr + bidx,     __ATOMIC_RELAXED, __HIP_MEMORY_SCOPE_AGENT);
      v[2*ks+1] = __hip_atomic_load(hr + bidx + 1, __ATOMIC_RELAXED, __HIP_MEMORY_SCOPE_AGENT);
    }
    __builtin_amdgcn_sched_barrier(0);   // pin: polls issued before x-MFMAs

    // ---- x-part MFMAs (K=512 from private LDS; overlaps poll flight) ----
    const char* xb = xpriv + (t & 1) * 16384;
    f32x4 acc[4] = {{0.f,0.f,0.f,0.f},{0.f,0.f,0.f,0.f},{0.f,0.f,0.f,0.f},{0.f,0.f,0.f,0.f}};
#pragma unroll
    for (int ks = 0; ks < 16; ++ks) {
      int ch = ks * 4 + kg;
      f16x8 a = *(const f16x8*)(xb + arow * 1024 + ((ch ^ (arow & 7)) << 4));
      acc[ks & 3] = __builtin_amdgcn_mfma_f32_16x16x32_f16(
          a, __builtin_bit_cast(f16x8, bw[ks]), acc[ks & 3], 0, 0, 0);
    }

    // ---- poll-check (implicit vmcnt wait absorbs staging + store acks) ----
    {
      unsigned tag = (unsigned)(t & 255);
      unsigned long long expect =
          (unsigned long long)(tag & 3)
        | ((unsigned long long)((tag >> 2) & 3) << 16)
        | ((unsigned long long)((tag >> 4) & 3) << 32)
        | ((unsigned long long)((tag >> 6) & 3) << 48);
      while (true) {
        bool ok = true;
#pragma unroll
        for (int i = 0; i < 32; ++i) ok &= ((v[i] & TAGMASK) == expect);
        if (__all(ok)) break;
        __builtin_amdgcn_s_sleep(1);
#pragma unroll
        for (int ks = 0; ks < 16; ++ks) {
          int bidx = (ks * 2 + (kg >> 1)) * 64 + c15 * 4 + (kg & 1) * 2;
          v[2*ks]   = __hip_atomic_load(hr + bidx,     __ATOMIC_RELAXED, __HIP_MEMORY_SCOPE_AGENT);
          v[2*ks+1] = __hip_atomic_load(hr + bidx + 1, __ATOMIC_RELAXED, __HIP_MEMORY_SCOPE_AGENT);
        }
      }
    }

    // ---- h-part MFMAs (polled regs ARE the A-fragments) ----
#pragma unroll
    for (int ks = 0; ks < 16; ++ks) {
      union { unsigned long long u[2]; f16x8 f; } tmp;
      tmp.u[0] = v[2*ks]; tmp.u[1] = v[2*ks+1];
      acc[ks & 3] = __builtin_amdgcn_mfma_f32_16x16x32_f16(
          tmp.f, __builtin_bit_cast(f16x8, bw[16 + ks]), acc[ks & 3], 0, 0, 0);
    }
    f32x4 zq;
#pragma unroll
    for (int q = 0; q < 4; ++q)
      zq[q] = acc[0][q] + acc[1][q] + acc[2][q] + acc[3][q];

    // ---- wave-local transpose: z[col c15][rows kg*4+q] (stride 20) ----
    *(f32x4*)(zwf + c15 * 20 + kg * 4) = zq;
    asm volatile("s_waitcnt lgkmcnt(0)" ::: "memory");
    __builtin_amdgcn_sched_barrier(0);

    // ---- gate combine: owner lane (orow, oj) reads 4 gates ----
    float h;
    {
      float z0 = zwf[(0 * 4 + oj) * 20 + orow] + bg[0];
      float z1 = zwf[(1 * 4 + oj) * 20 + orow] + bg[1];
      float z2 = zwf[(2 * 4 + oj) * 20 + orow] + bg[2];
      float z3 = zwf[(3 * 4 + oj) * 20 + orow] + bg[3];
      float ig = 1.f / (1.f + __expf(-z0));
      float fg = 1.f / (1.f + __expf(-z1));
      float e2 = __expf(2.f * z2);
      float gg = (e2 - 1.f) / (e2 + 1.f);
      float og = 1.f / (1.f + __expf(-z3));
      c = fg * c + ig * gg;
      float ec = __expf(2.f * c);
      float th = (ec - 1.f) / (ec + 1.f);
      h = og * th;
    }

    // ---- publish tagged h: one 8B atomic store per row (4 units) ----
    {
      unsigned ptag = (unsigned)((t + 1) & 255);
      union { _Float16 f; unsigned short s; } cv;
      cv.f = (_Float16)h;
      unsigned tagged = ((unsigned)cv.s & 0xFFFCu) | ((ptag >> (2 * oj)) & 3u);
      unsigned pair = (tagged & 0xFFFFu) | ((unsigned)__shfl_xor((int)tagged, 1, 64) << 16);
      unsigned other = (unsigned)__shfl_xor((int)pair, 2, 64);
      if (oj == 0) {
        unsigned long long u = (unsigned long long)pair | ((unsigned long long)other << 32);
        unsigned long long* hbw = (unsigned long long*)(hb + (size_t)((t + 1) & 1) * 8192);
        __hip_atomic_store(hbw + ut * 64 + orow * 4 + w, u,
                           __ATOMIC_RELAXED, __HIP_MEMORY_SCOPE_AGENT);
      }
    }

    // ---- stage x[t+2] -> parity (t&1) (all x ds_reads already retired) ----
    if (t + 2 < T_) {
      const int t_n = dir ? (T_ - 3 - t) : (t + 2);
      char* dst = xpriv + (t & 1) * 16384;
      for (int r = 0; r < 16; ++r) {
        const char* src = (const char*)(xf + ((size_t)(bt * 16 + r) * T_ + t_n) * D_)
                          + ((lane ^ (r & 7)) << 4);
        GLD_LDS16(src, dst + r * 1024);
      }
    }

    // y store (off critical path; acks absorbed by next poll)
    if (ug0 < U_)
      y[((size_t)(bt * 16 + orow) * T_ + t_x) * (2 * U_) + dir * U_ + ug0] = h;
  }
}

// ============================ launcher ============================
extern "C" void kernel_launch(void* const* d_in, const int* in_sizes, int n_in,
                              void* d_out, int out_size, void* d_ws, size_t ws_size,
                              hipStream_t stream) {
  (void)in_sizes; (void)n_in; (void)out_size; (void)ws_size;
  const float* x    = (const float*)d_in[0];
  const float* h_f  = (const float*)d_in[1];
  const float* c_f  = (const float*)d_in[2];
  const float* h_b  = (const float*)d_in[3];
  const float* c_b  = (const float*)d_in[4];
  const float* Wk_f = (const float*)d_in[5];
  const float* Wr_f = (const float*)d_in[6];
  const float* b_f  = (const float*)d_in[7];
  const float* Wk_b = (const float*)d_in[8];
  const float* Wr_b = (const float*)d_in[9];
  const float* b_b  = (const float*)d_in[10];

  char* ws = (char*)d_ws;
  _Float16* xf    = (_Float16*)(ws + OFF_X);
  _Float16* Wc    = (_Float16*)(ws + OFF_W);
  float*    bcomb = (float*)   (ws + OFF_B);
  _Float16* hbuf  = (_Float16*)(ws + OFF_H);
  float*    y     = (float*)d_out;

  prep_x<<<4096, 256, 0, stream>>>(x, xf);
  prep_w<<<2048, 256, 0, stream>>>(Wk_f, Wr_f, Wk_b, Wr_b, b_f, b_b, Wc, bcomb);
  prep_hb<<<256, 256, 0, stream>>>(h_f, h_b, hbuf);

  static bool attr_done = false;
  if (!attr_done) {
    (void)hipFuncSetAttribute((const void*)lstm_scan,
                              hipFuncAttributeMaxDynamicSharedMemorySize, LDS_BYTES);
    attr_done = true;
  }
  lstm_scan<<<256, 256, LDS_BYTES, stream>>>(xf, Wc, bcomb, c_f, c_b, hbuf, y);
}

// Round 9
// 599.828 us; speedup vs baseline: 2.4142x; 2.4142x over previous
//
#include <hip/hip_runtime.h>
#include <hip/hip_fp16.h>
#include <cstdint>
#include <cstddef>

// Problem dims
#define B_    64
#define T_    256
#define D_    512
#define U_    500
#define UP_   512            // padded units
#define NCOL_ 2048           // 4*UP_
#define K_    1024           // D_ + UP_

typedef _Float16 f16x8 __attribute__((ext_vector_type(8)));
typedef float    f32x4 __attribute__((ext_vector_type(4)));
typedef int      i32x4 __attribute__((ext_vector_type(4)));

// ---- workspace layout (bytes) ----
#define OFF_X   0ull                         // x fp16: 64*256*512*2        = 16777216
#define OFF_W   16777216ull                  // Wcomb fp16: 2*2048*1024*2   = 8388608
#define OFF_B   25165824ull                  // bcomb f32: 2*2048*4         = 16384
#define OFF_H   25182208ull                  // h_buf fp16: 8*2*8192*2      = 262144

// ---- LDS layout (bytes), dynamic 72KB ----
#define LXA  0               // x tile buf0: 16 rows * 1024B (swizzled)
#define LXB  16384           // x tile buf1
#define LZP0 32768           // z partials parity0: 4 waves * 1280 f32 = 20480B
#define LZP1 53248           // z partials parity1
#define LDS_BYTES 73728

#define TAGMASK 0x0003000300030003ull

#define GLD_LDS16(g, l) \
  __builtin_amdgcn_global_load_lds((const __attribute__((address_space(1))) void*)(g), \
                                   (__attribute__((address_space(3))) void*)(l), 16, 0, 0)

// ============================ prep kernels ============================

__global__ void prep_x(const float* __restrict__ x, _Float16* __restrict__ xf) {
  size_t base = ((size_t)blockIdx.x * 256 + threadIdx.x) * 8;
  const float4* p = (const float4*)(x + base);
  float4 a = p[0], b = p[1];
  f16x8 v;
  v[0] = (_Float16)a.x; v[1] = (_Float16)a.y; v[2] = (_Float16)a.z; v[3] = (_Float16)a.w;
  v[4] = (_Float16)b.x; v[5] = (_Float16)b.y; v[6] = (_Float16)b.z; v[7] = (_Float16)b.w;
  *(f16x8*)(xf + base) = v;
}

__global__ void prep_w(const float* __restrict__ Wkf, const float* __restrict__ Wrf,
                       const float* __restrict__ Wkb, const float* __restrict__ Wrb,
                       const float* __restrict__ bf,  const float* __restrict__ bb,
                       _Float16* __restrict__ Wc, float* __restrict__ bcomb) {
  size_t gid = (size_t)blockIdx.x * 256 + threadIdx.x;
  int dir = (int)(gid >> 18);
  int rem = (int)(gid & 262143);
  int col = rem >> 7;
  int k0  = (rem & 127) << 3;
  const float* Wk = dir ? Wkb : Wkf;
  const float* Wr = dir ? Wrb : Wrf;
  int g = (col >> 4) & 3, du = col & 15, utc = col >> 6;
  int ug = utc * 16 + du;
  bool valid = (ug < U_);
  int c4 = g * U_ + ug;
  f16x8 out;
#pragma unroll
  for (int kk = 0; kk < 8; ++kk) {
    int k = k0 + kk;
    float v = 0.f;
    if (valid) {
      if (k < D_) v = Wk[(size_t)k * (4 * U_) + c4];
      else { int u = k - D_; if (u < U_) v = Wr[(size_t)u * (4 * U_) + c4]; }
    }
    out[kk] = (_Float16)v;
  }
  *(f16x8*)(Wc + ((size_t)dir * NCOL_ + col) * K_ + k0) = out;

  if (gid < 4096) {
    int d2 = (int)(gid >> 11), c2 = (int)(gid & 2047);
    int g2 = (c2 >> 4) & 3, du2 = c2 & 15, ut2 = c2 >> 6;
    int ug2 = ut2 * 16 + du2;
    const float* bs = d2 ? bb : bf;
    bcomb[gid] = (ug2 < U_) ? bs[g2 * U_ + ug2] : 0.f;
  }
}

// h_buf layout: [gi][parity][p=u>>4][row][u&15] fp16, 2-bit step tags in-band.
__global__ void prep_hb(const float* __restrict__ hf, const float* __restrict__ hb,
                        _Float16* __restrict__ hbuf) {
  int idx = blockIdx.x * 256 + threadIdx.x;    // < 65536
  int dir = idx >> 15;
  int rem = idx & 32767;
  int bt = rem >> 13, r = (rem >> 9) & 15, u = rem & 511;
  const float* h0 = dir ? hb : hf;
  float v = (u < U_) ? h0[(size_t)(bt * 16 + r) * U_ + u] : 0.f;
  int gi = dir * 4 + bt;
  union { _Float16 f; unsigned short s; } cv;
  cv.f = (_Float16)v;
  cv.s &= 0xFFFC;   // tag = 0
  ((unsigned short*)hbuf)[(size_t)(gi * 2 + 0) * 8192 + (u >> 4) * 256 + r * 16 + (u & 15)] = cv.s;
}

// ============================ persistent scan ============================
// 256 blocks (1/CU), 256 threads. Block = (dir, bt, ut): 16 rows x 16 units.
// Symmetric waves: wave w owns x-K slice [w*128,+128) AND h-K slice
// [512+w*128,+128). W fragments PINNED in VGPRs (anti-remat asm, R8-proven).
// Per step: poll-issue -> x-MFMA (covers load flight) -> poll-check (vmcnt0
// absorbs store acks + staging) -> h-MFMA -> zp write (dbuf parity) ->
// lgkm-only barrier -> stage x[t+2] -> gate -> tagged publish -> y.
// ONE barrier/step, no vmcnt drain outside the poll.
__global__ __launch_bounds__(256, 1) void lstm_scan(
    const _Float16* __restrict__ xf, const _Float16* __restrict__ Wc,
    const float* __restrict__ bc, const float* __restrict__ cf,
    const float* __restrict__ cb, _Float16* __restrict__ hbuf,
    float* __restrict__ y)
{
  extern __shared__ __align__(16) char lds[];
  const int tid  = threadIdx.x;
  const int lane = tid & 63;
  const int w    = tid >> 6;        // wave id == K-slice id
  const int bid  = blockIdx.x;
  const int grp  = bid & 7;         // group -> same XCD under round-robin (perf only)
  const int dir  = grp >> 2;
  const int bt   = grp & 3;
  const int ut   = bid >> 3;

  const int c15  = lane & 15;       // B col-in-tile / A row
  const int kg   = lane >> 4;       // k-group
  const int arow = c15;

  // ---- B-fragments -> PINNED registers (32 x 16B = 128 VGPR) ----
  // bw[ct*4+ks] = x-slice frag (K offset w*128+ks*32), bw[16+ct*4+ks] = h-slice
  i32x4 bw[32];
  {
    const _Float16* wbase = Wc + ((size_t)dir * NCOL_ + (size_t)ut * 64) * K_;
#pragma unroll
    for (int ct = 0; ct < 4; ++ct)
#pragma unroll
      for (int ks = 0; ks < 4; ++ks) {
        const _Float16* cl = wbase + (size_t)(ct * 16 + c15) * K_ + w * 128 + ks * 32 + kg * 8;
        bw[ct * 4 + ks]      = *(const i32x4*)cl;
        bw[16 + ct * 4 + ks] = *(const i32x4*)(cl + 512);
      }
#pragma unroll
    for (int i = 0; i < 32; ++i)
      asm volatile("" : "+v"(bw[i]));   // opaque: cannot be rematerialized
  }

  const int r0 = tid >> 4, du0 = tid & 15;
  const int ug0 = ut * 16 + du0;
  float bg[4];
#pragma unroll
  for (int g = 0; g < 4; ++g) bg[g] = bc[dir * NCOL_ + ut * 64 + g * 16 + du0];
  const float* cin = dir ? cb : cf;
  float c = (ug0 < U_) ? cin[(size_t)(bt * 16 + r0) * U_ + ug0] : 0.f;

  const int gi = dir * 4 + bt;
  _Float16* hb = hbuf + (size_t)gi * 2 * 8192;

  // stage x[0] -> bufA, x[1] -> bufB (wave w stages rows 4w..4w+3)
#pragma unroll
  for (int tt = 0; tt < 2; ++tt) {
    const int t_x0 = dir ? (T_ - 1 - tt) : tt;
    char* dst = lds + (tt ? LXB : LXA);
    for (int rr = 0; rr < 4; ++rr) {
      int r = w * 4 + rr;
      const char* src = (const char*)(xf + ((size_t)(bt * 16 + r) * T_ + t_x0) * D_)
                        + ((lane ^ (r & 7)) << 4);
      GLD_LDS16(src, dst + r * 1024);
    }
  }
  __syncthreads();   // full drain: x[0]/x[1] resident

#pragma unroll 1
  for (int t = 0; t < T_; ++t) {
    const int t_x = dir ? (T_ - 1 - t) : t;

    // ---- poll-issue: 8 agent-coherent u64 loads (this wave's h K-slice) ----
    const unsigned long long* hr =
        (const unsigned long long*)(hb + (size_t)(t & 1) * 8192);
    unsigned long long v[8];
#pragma unroll
    for (int ks = 0; ks < 4; ++ks) {
      int ch = w * 16 + ks * 4 + kg;
      int bidx = (ch >> 1) * 64 + arow * 4 + (ch & 1) * 2;
      v[2*ks]   = __hip_atomic_load(hr + bidx,     __ATOMIC_RELAXED, __HIP_MEMORY_SCOPE_AGENT);
      v[2*ks+1] = __hip_atomic_load(hr + bidx + 1, __ATOMIC_RELAXED, __HIP_MEMORY_SCOPE_AGENT);
    }
    __builtin_amdgcn_sched_barrier(0);   // pin: polls issued before x-MFMAs

    // ---- x-part MFMAs (overlap the poll flight) ----
    const char* xb = lds + ((t & 1) ? LXB : LXA);
    f32x4 acc[4] = {{0.f,0.f,0.f,0.f},{0.f,0.f,0.f,0.f},{0.f,0.f,0.f,0.f},{0.f,0.f,0.f,0.f}};
#pragma unroll
    for (int ks = 0; ks < 4; ++ks) {
      int ch = w * 16 + ks * 4 + kg;
      f16x8 a = *(const f16x8*)(xb + arow * 1024 + ((ch ^ (arow & 7)) << 4));
#pragma unroll
      for (int ct = 0; ct < 4; ++ct)
        acc[ct] = __builtin_amdgcn_mfma_f32_16x16x32_f16(
            a, __builtin_bit_cast(f16x8, bw[ct * 4 + ks]), acc[ct], 0, 0, 0);
    }

    // ---- poll-check (vmcnt(0) here absorbs store acks + staging) ----
    {
      unsigned tag = (unsigned)(t & 255);
      unsigned long long expect =
          (unsigned long long)(tag & 3)
        | ((unsigned long long)((tag >> 2) & 3) << 16)
        | ((unsigned long long)((tag >> 4) & 3) << 32)
        | ((unsigned long long)((tag >> 6) & 3) << 48);
      while (true) {
        bool ok = true;
#pragma unroll
        for (int i = 0; i < 8; ++i) ok &= ((v[i] & TAGMASK) == expect);
        if (__all(ok)) break;
        __builtin_amdgcn_s_sleep(1);
#pragma unroll
        for (int ks = 0; ks < 4; ++ks) {
          int ch = w * 16 + ks * 4 + kg;
          int bidx = (ch >> 1) * 64 + arow * 4 + (ch & 1) * 2;
          v[2*ks]   = __hip_atomic_load(hr + bidx,     __ATOMIC_RELAXED, __HIP_MEMORY_SCOPE_AGENT);
          v[2*ks+1] = __hip_atomic_load(hr + bidx + 1, __ATOMIC_RELAXED, __HIP_MEMORY_SCOPE_AGENT);
        }
      }
    }

    // ---- h-part MFMAs (polled regs ARE the A-fragments) ----
#pragma unroll
    for (int ks = 0; ks < 4; ++ks) {
      union { unsigned long long u[2]; f16x8 f; } tmp;
      tmp.u[0] = v[2*ks]; tmp.u[1] = v[2*ks+1];
#pragma unroll
      for (int ct = 0; ct < 4; ++ct)
        acc[ct] = __builtin_amdgcn_mfma_f32_16x16x32_f16(
            tmp.f, __builtin_bit_cast(f16x8, bw[16 + ct * 4 + ks]), acc[ct], 0, 0, 0);
    }

    // ---- write K-partials: zp[parity][w][col][row20] ----
    float* zpw = (float*)(lds + ((t & 1) ? LZP1 : LZP0)) + w * 1280;
#pragma unroll
    for (int ct = 0; ct < 4; ++ct)
      *(f32x4*)(zpw + (ct * 16 + c15) * 20 + kg * 4) = acc[ct];

    // ---- ONE barrier/step: LDS-only drain, no vmcnt ----
    asm volatile("s_waitcnt lgkmcnt(0)" ::: "memory");
    __builtin_amdgcn_s_barrier();

    // stage x[t+2] -> buf[t&1] (flight covered by poll(t+1)'s vmcnt0)
    if (t + 2 < T_) {
      const int t_n = dir ? (T_ - 3 - t) : (t + 2);
      char* dst = lds + ((t & 1) ? LXB : LXA);
      for (int rr = 0; rr < 4; ++rr) {
        int r = w * 4 + rr;
        const char* src = (const char*)(xf + ((size_t)(bt * 16 + r) * T_ + t_n) * D_)
                          + ((lane ^ (r & 7)) << 4);
        GLD_LDS16(src, dst + r * 1024);
      }
    }

    // ---- gate combine: thread (r0, du0); 4-way K-reduction fused ----
    float h;
    {
      const float* zr = (const float*)(lds + ((t & 1) ? LZP1 : LZP0));
      float z[4];
#pragma unroll
      for (int g = 0; g < 4; ++g) {
        int cb2 = (g * 16 + du0) * 20 + r0;
        z[g] = bg[g] + zr[cb2] + zr[1280 + cb2] + zr[2560 + cb2] + zr[3840 + cb2];
      }
      float ig = 1.f / (1.f + __expf(-z[0]));
      float fg = 1.f / (1.f + __expf(-z[1]));
      float e2 = __expf(2.f * z[2]);
      float gg = (e2 - 1.f) / (e2 + 1.f);
      float og = 1.f / (1.f + __expf(-z[3]));
      c = fg * c + ig * gg;
      float ec = __expf(2.f * c);
      float th = (ec - 1.f) / (ec + 1.f);
      h = og * th;
    }

    // ---- publish tagged h: 8B atomic store per 4 units ----
    {
      unsigned ptag = (unsigned)((t + 1) & 255);
      union { _Float16 f; unsigned short s; } cv;
      cv.f = (_Float16)h;
      unsigned tagged = ((unsigned)cv.s & 0xFFFCu) | ((ptag >> (2 * (du0 & 3))) & 3u);
      unsigned pair = tagged | ((unsigned)__shfl_xor((int)tagged, 1, 64) << 16);
      unsigned other = (unsigned)__shfl_xor((int)pair, 2, 64);
      if ((du0 & 3) == 0) {
        unsigned long long u = (unsigned long long)pair | ((unsigned long long)other << 32);
        unsigned long long* hbw = (unsigned long long*)(hb + (size_t)((t + 1) & 1) * 8192);
        __hip_atomic_store(hbw + ut * 64 + r0 * 4 + (du0 >> 2), u,
                           __ATOMIC_RELAXED, __HIP_MEMORY_SCOPE_AGENT);
      }
    }

    // y store (off critical path; ack absorbed by next poll)
    if (ug0 < U_)
      y[((size_t)(bt * 16 + r0) * T_ + t_x) * (2 * U_) + dir * U_ + ug0] = h;
  }
}

// ============================ launcher ============================
extern "C" void kernel_launch(void* const* d_in, const int* in_sizes, int n_in,
                              void* d_out, int out_size, void* d_ws, size_t ws_size,
                              hipStream_t stream) {
  (void)in_sizes; (void)n_in; (void)out_size; (void)ws_size;
  const float* x    = (const float*)d_in[0];
  const float* h_f  = (const float*)d_in[1];
  const float* c_f  = (const float*)d_in[2];
  const float* h_b  = (const float*)d_in[3];
  const float* c_b  = (const float*)d_in[4];
  const float* Wk_f = (const float*)d_in[5];
  const float* Wr_f = (const float*)d_in[6];
  const float* b_f  = (const float*)d_in[7];
  const float* Wk_b = (const float*)d_in[8];
  const float* Wr_b = (const float*)d_in[9];
  const float* b_b  = (const float*)d_in[10];

  char* ws = (char*)d_ws;
  _Float16* xf    = (_Float16*)(ws + OFF_X);
  _Float16* Wc    = (_Float16*)(ws + OFF_W);
  float*    bcomb = (float*)   (ws + OFF_B);
  _Float16* hbuf  = (_Float16*)(ws + OFF_H);
  float*    y     = (float*)d_out;

  prep_x<<<4096, 256, 0, stream>>>(x, xf);
  prep_w<<<2048, 256, 0, stream>>>(Wk_f, Wr_f, Wk_b, Wr_b, b_f, b_b, Wc, bcomb);
  prep_hb<<<256, 256, 0, stream>>>(h_f, h_b, hbuf);

  static bool attr_done = false;
  if (!attr_done) {
    (void)hipFuncSetAttribute((const void*)lstm_scan,
                              hipFuncAttributeMaxDynamicSharedMemorySize, LDS_BYTES);
    attr_done = true;
  }
  lstm_scan<<<256, 256, LDS_BYTES, stream>>>(xf, Wc, bcomb, c_f, c_b, hbuf, y);
}